// Round 2
// baseline (2029.535 us; speedup 1.0000x reference)
//
#include <hip/hip_runtime.h>
#include <hip/hip_bf16.h>
#include <hip/hip_cooperative_groups.h>

namespace cg = cooperative_groups;

#define DD 128

typedef __attribute__((ext_vector_type(8))) short bfrag8;
typedef __attribute__((ext_vector_type(4))) float f32x4;

__device__ __forceinline__ float bf16lo(unsigned int u) {
    union { unsigned int i; float f; } c; c.i = u << 16; return c.f;
}
__device__ __forceinline__ float bf16hi(unsigned int u) {
    union { unsigned int i; float f; } c; c.i = u & 0xffff0000u; return c.f;
}
__device__ __forceinline__ unsigned short f2bf(float f) {
    union { float f; unsigned int i; } c; c.f = f;
    unsigned int x = c.i;
    unsigned int r = (x + 0x7fffu + ((x >> 16) & 1u)) >> 16;  // RNE
    return (unsigned short)r;
}

// ============================================================================
// Mega cooperative kernel: whole GIN forward in ONE dispatch.
// LDS layout (52224 B total -> 3 blocks/CU):
//   [0, 34816)        wl : W tile, 128 rows x 136 ushorts (16B-aligned rows)
//   [34816, 52224)    zl : z tile,  64 rows x 136 ushorts
//   scan/reduce phases alias the zl region (scani: 1KB ints, red: 2KB floats)
// ============================================================================
struct MegaArgs {
    const float *features, *W, *bias, *eps, *g1, *b1, *g2, *b2;
    const int *src, *dst;
    float* out;
    int Nn, E, ntiles, nchunk, total4;
    float invN;
    int *deg, *cursor, *row_local, *partials, *pscan, *csr;
    unsigned int* hb;
    unsigned short* Wt;
    float* y;
    float* stats;  // [3][4][128]: s1sum, s1sq, s2sum, s2sq per layer
};

__launch_bounds__(256, 3)
__global__ void k_mega(MegaArgs a) {
    cg::grid_group grid = cg::this_grid();
    __shared__ __align__(16) char smem[52224];
    unsigned short* wl = (unsigned short*)smem;
    unsigned short* zl = (unsigned short*)(smem + 34816);
    int*   scani = (int*)(smem + 34816);
    float* red   = (float*)(smem + 34816);

    const int tid  = threadIdx.x;
    const int bid  = blockIdx.x;
    const int nb   = gridDim.x;
    const int gsz  = nb * 256;
    const int gtid = bid * 256 + tid;
    const int lane = tid & 63, wv = tid >> 6;

    // ---- P0: zero deg/cursor/stats ----
    for (int i = gtid; i < a.Nn; i += gsz) { a.deg[i] = 0; a.cursor[i] = 0; }
    for (int i = gtid; i < 3 * 512; i += gsz) a.stats[i] = 0.f;
    grid.sync();

    // ---- P1: degree histogram + feature convert + W convert ----
    for (int i = gtid; i < a.E; i += gsz) atomicAdd(&a.deg[a.dst[i]], 1);
    for (int i = gtid; i < a.total4; i += gsz) {
        float4 v = ((const float4*)a.features)[i];
        ((float4*)a.out)[i] = v;
        unsigned int lo = (unsigned int)f2bf(v.x) | ((unsigned int)f2bf(v.y) << 16);
        unsigned int hi = (unsigned int)f2bf(v.z) | ((unsigned int)f2bf(v.w) << 16);
        ((uint2*)a.hb)[i] = make_uint2(lo, hi);
    }
    for (int i = gtid; i < 3 * 128 * 128; i += gsz) {
        int l = i >> 14, r = i & 16383, k = r >> 7, n = r & 127;
        a.Wt[(l << 14) + n * 128 + k] = f2bf(a.W[i]);
    }
    grid.sync();

    // ---- P2a: per-512-chunk exclusive scans of deg ----
    for (int c = bid; c < a.nchunk; c += nb) {
        int base = c << 9;
        int i0 = base + 2 * tid, i1 = i0 + 1;
        int d0 = (i0 < a.Nn) ? a.deg[i0] : 0;
        int d1 = (i1 < a.Nn) ? a.deg[i1] : 0;
        scani[tid] = d0 + d1;
        __syncthreads();
        for (int off = 1; off < 256; off <<= 1) {
            int t = (tid >= off) ? scani[tid - off] : 0;
            __syncthreads();
            scani[tid] += t;
            __syncthreads();
        }
        int incl = scani[tid];
        int excl = incl - d0 - d1;
        if (i0 < a.Nn) a.row_local[i0] = excl;
        if (i1 < a.Nn) a.row_local[i1] = excl + d0;
        if (tid == 255) a.partials[c] = incl;
        __syncthreads();
    }
    grid.sync();

    // ---- P2b: top-level scan of chunk partials (block 0; nchunk <= 256) ----
    if (bid == 0) {
        int p = (tid < a.nchunk) ? a.partials[tid] : 0;
        scani[tid] = p;
        __syncthreads();
        for (int off = 1; off < 256; off <<= 1) {
            int t = (tid >= off) ? scani[tid - off] : 0;
            __syncthreads();
            scani[tid] += t;
            __syncthreads();
        }
        if (tid < a.nchunk) a.pscan[tid] = scani[tid] - p;
    }
    grid.sync();

    // ---- P3: scatter edges into CSR ----
    for (int i = gtid; i < a.E; i += gsz) {
        int d = a.dst[i];
        int pos = a.row_local[d] + a.pscan[d >> 9] + atomicAdd(&a.cursor[d], 1);
        a.csr[pos] = a.src[i];
    }
    grid.sync();

    // ---- layers ----
    for (int l = 0; l < 3; ++l) {
        float* stl = a.stats + l * 512;

        // stage this layer's W^T (bf16) into LDS, persistent across tiles
        const unsigned short* Wl = a.Wt + (l << 14);
        for (int i = tid; i < 2048; i += 256) {
            int n = i >> 4, c = i & 15;
            *(uint4*)&wl[n * 136 + c * 8] = *(const uint4*)&Wl[n * 128 + c * 8];
        }
        float e1v = 1.0f + a.eps[l];
        __syncthreads();

        // ---- P5: fused gather -> GEMM -> bias -> y write -> BN1 stats ----
        for (int t = bid; t < a.ntiles; t += nb) {
            int m0 = t << 6;
            // gather z rows into zl (each wave: 16 rows, one row per pass)
            for (int rr = wv; rr < 64; rr += 4) {
                int v = m0 + rr;
                unsigned int packed = 0;
                if (v < a.Nn) {
                    unsigned int hs = a.hb[(size_t)v * 64 + lane];
                    float ax = e1v * bf16lo(hs), ay = e1v * bf16hi(hs);
                    int beg = a.row_local[v] + a.pscan[v >> 9];
                    int vn = v + 1;
                    int end = (vn < a.Nn) ? (a.row_local[vn] + a.pscan[vn >> 9]) : a.E;
                    int e = beg;
                    for (; e + 3 < end; e += 4) {
                        int u0 = a.csr[e], u1 = a.csr[e + 1], u2 = a.csr[e + 2], u3 = a.csr[e + 3];
                        unsigned int h0 = a.hb[(size_t)u0 * 64 + lane];
                        unsigned int h1 = a.hb[(size_t)u1 * 64 + lane];
                        unsigned int h2 = a.hb[(size_t)u2 * 64 + lane];
                        unsigned int h3 = a.hb[(size_t)u3 * 64 + lane];
                        ax += bf16lo(h0) + bf16lo(h1) + bf16lo(h2) + bf16lo(h3);
                        ay += bf16hi(h0) + bf16hi(h1) + bf16hi(h2) + bf16hi(h3);
                    }
                    for (; e < end; ++e) {
                        unsigned int hu = a.hb[(size_t)a.csr[e] * 64 + lane];
                        ax += bf16lo(hu); ay += bf16hi(hu);
                    }
                    packed = (unsigned int)f2bf(ax) | ((unsigned int)f2bf(ay) << 16);
                }
                ((unsigned int*)&zl[rr * 136])[lane] = packed;
            }
            __syncthreads();

            // MFMA: 64x128 tile, K=128
            int tcol = lane & 15, quad = lane >> 4;
            f32x4 acc[4][2];
            #pragma unroll
            for (int m = 0; m < 4; m++)
                #pragma unroll
                for (int n = 0; n < 2; n++) acc[m][n] = (f32x4){0.f, 0.f, 0.f, 0.f};
            #pragma unroll
            for (int kk = 0; kk < 128; kk += 32) {
                int kb = kk + quad * 8;
                bfrag8 af[4], bf[2];
                #pragma unroll
                for (int mt = 0; mt < 4; mt++)
                    af[mt] = *(const bfrag8*)&zl[(16 * mt + tcol) * 136 + kb];
                #pragma unroll
                for (int nt = 0; nt < 2; nt++)
                    bf[nt] = *(const bfrag8*)&wl[(32 * wv + 16 * nt + tcol) * 136 + kb];
                #pragma unroll
                for (int mt = 0; mt < 4; mt++)
                    #pragma unroll
                    for (int nt = 0; nt < 2; nt++)
                        acc[mt][nt] = __builtin_amdgcn_mfma_f32_16x16x32_bf16(af[mt], bf[nt], acc[mt][nt], 0, 0, 0);
            }

            // epilogue: bias, y write, BN1 partial stats
            #pragma unroll
            for (int nt = 0; nt < 2; nt++) {
                int col = 32 * wv + 16 * nt + tcol;
                float bcol = a.bias[l * 128 + col];
                float psum = 0.f, psq = 0.f;
                #pragma unroll
                for (int mt = 0; mt < 4; mt++) {
                    #pragma unroll
                    for (int r = 0; r < 4; r++) {
                        int row = m0 + 16 * mt + quad * 4 + r;
                        float val = acc[mt][nt][r] + bcol;
                        if (row < a.Nn) {
                            a.y[(size_t)row * 128 + col] = val;
                            psum += val;
                            psq += val * val;
                        }
                    }
                }
                psum += __shfl_xor(psum, 16); psq += __shfl_xor(psq, 16);
                psum += __shfl_xor(psum, 32); psq += __shfl_xor(psq, 32);
                if (lane < 16) {
                    atomicAdd(&stl[col], psum);
                    atomicAdd(&stl[128 + col], psq);
                }
            }
            __syncthreads();  // before next tile's gather overwrites zl
        }
        grid.sync();

        // ---- P6: BN1 finalize (local) + BN2 stats over relu(aff1(y)) ----
        if (tid < 128) {
            float m = stl[tid] * a.invN;
            float var = stl[128 + tid] * a.invN - m * m;
            float rstd = rsqrtf(var + 1e-5f);
            float s = a.g1[l * 128 + tid] * rstd;
            red[tid] = s;
            red[128 + tid] = a.b1[l * 128 + tid] - m * s;
            red[256 + tid] = 0.f;   // block-local BN2 sum accum
            red[384 + tid] = 0.f;   // block-local BN2 sq accum
        }
        __syncthreads();
        int cbase = (4 * lane) & 127;
        float s1r[4], sh1r[4];
        #pragma unroll
        for (int j = 0; j < 4; j++) { s1r[j] = red[cbase + j]; sh1r[j] = red[128 + cbase + j]; }
        float ps[4] = {0.f, 0.f, 0.f, 0.f}, pq[4] = {0.f, 0.f, 0.f, 0.f};
        for (int i = gtid; i < a.total4; i += gsz) {
            float4 v = ((const float4*)a.y)[i];
            float t0 = fmaxf(v.x * s1r[0] + sh1r[0], 0.f);
            float t1 = fmaxf(v.y * s1r[1] + sh1r[1], 0.f);
            float t2 = fmaxf(v.z * s1r[2] + sh1r[2], 0.f);
            float t3 = fmaxf(v.w * s1r[3] + sh1r[3], 0.f);
            ps[0] += t0; pq[0] += t0 * t0;
            ps[1] += t1; pq[1] += t1 * t1;
            ps[2] += t2; pq[2] += t2 * t2;
            ps[3] += t3; pq[3] += t3 * t3;
        }
        #pragma unroll
        for (int j = 0; j < 4; j++) {
            ps[j] += __shfl_xor(ps[j], 32);
            pq[j] += __shfl_xor(pq[j], 32);
        }
        if (lane < 32) {
            #pragma unroll
            for (int j = 0; j < 4; j++) {
                atomicAdd(&red[256 + cbase + j], ps[j]);
                atomicAdd(&red[384 + cbase + j], pq[j]);
            }
        }
        __syncthreads();
        if (tid < 128) {
            atomicAdd(&stl[256 + tid], red[256 + tid]);
            atomicAdd(&stl[384 + tid], red[384 + tid]);
        }
        grid.sync();

        // ---- P7: apply both BNs, write fp32 out slab + bf16 h ----
        if (tid < 128) {
            float m1 = stl[tid] * a.invN;
            float v1 = stl[128 + tid] * a.invN - m1 * m1;
            float r1 = rsqrtf(v1 + 1e-5f);
            float s1 = a.g1[l * 128 + tid] * r1;
            red[tid] = s1;
            red[128 + tid] = a.b1[l * 128 + tid] - m1 * s1;
            float m2 = stl[256 + tid] * a.invN;
            float v2 = stl[384 + tid] * a.invN - m2 * m2;
            float r2 = rsqrtf(v2 + 1e-5f);
            float s2 = a.g2[l * 128 + tid] * r2;
            red[256 + tid] = s2;
            red[384 + tid] = a.b2[l * 128 + tid] - m2 * s2;
        }
        __syncthreads();
        float s1a[4], sh1a[4], s2a[4], sh2a[4];
        #pragma unroll
        for (int j = 0; j < 4; j++) {
            s1a[j]  = red[cbase + j];       sh1a[j] = red[128 + cbase + j];
            s2a[j]  = red[256 + cbase + j]; sh2a[j] = red[384 + cbase + j];
        }
        float* outl = a.out + (size_t)(l + 1) * a.Nn * DD;
        for (int i = gtid; i < a.total4; i += gsz) {
            float4 v = ((const float4*)a.y)[i];
            float t0 = fmaxf(v.x * s1a[0] + sh1a[0], 0.f);
            float t1 = fmaxf(v.y * s1a[1] + sh1a[1], 0.f);
            float t2 = fmaxf(v.z * s1a[2] + sh1a[2], 0.f);
            float t3 = fmaxf(v.w * s1a[3] + sh1a[3], 0.f);
            float o0 = fmaxf(t0 * s2a[0] + sh2a[0], 0.f);
            float o1 = fmaxf(t1 * s2a[1] + sh2a[1], 0.f);
            float o2 = fmaxf(t2 * s2a[2] + sh2a[2], 0.f);
            float o3 = fmaxf(t3 * s2a[3] + sh2a[3], 0.f);
            ((float4*)outl)[i] = make_float4(o0, o1, o2, o3);
            unsigned int lo = (unsigned int)f2bf(o0) | ((unsigned int)f2bf(o1) << 16);
            unsigned int hi = (unsigned int)f2bf(o2) | ((unsigned int)f2bf(o3) << 16);
            ((uint2*)a.hb)[i] = make_uint2(lo, hi);
        }
        grid.sync();
    }
}

// ============================================================================
// Fallback path: round-1 kernels (known good) in case cooperative launch fails
// ============================================================================
__global__ void k_hist(const int* __restrict__ dst, int* __restrict__ deg, int E) {
    int i = blockIdx.x * blockDim.x + threadIdx.x;
    if (i < E) atomicAdd(&deg[dst[i]], 1);
}

__global__ void k_scan1(const int* __restrict__ deg, int* __restrict__ partials, int Nn) {
    __shared__ int s[1024];
    int i = blockIdx.x * 1024 + threadIdx.x;
    s[threadIdx.x] = (i < Nn) ? deg[i] : 0;
    __syncthreads();
    for (int off = 512; off > 0; off >>= 1) {
        if (threadIdx.x < off) s[threadIdx.x] += s[threadIdx.x + off];
        __syncthreads();
    }
    if (threadIdx.x == 0) partials[blockIdx.x] = s[0];
}

__global__ void k_scan2(const int* __restrict__ partials, int* __restrict__ pscan, int nb) {
    if (threadIdx.x == 0) {
        int acc = 0;
        for (int i = 0; i < nb; i++) { pscan[i] = acc; acc += partials[i]; }
    }
}

__global__ void k_scan3(const int* __restrict__ deg, const int* __restrict__ pscan,
                        int* __restrict__ row_start, int Nn, int E) {
    __shared__ int s[1024];
    int i = blockIdx.x * 1024 + threadIdx.x;
    int v = (i < Nn) ? deg[i] : 0;
    s[threadIdx.x] = v;
    __syncthreads();
    for (int off = 1; off < 1024; off <<= 1) {
        int t = (threadIdx.x >= off) ? s[threadIdx.x - off] : 0;
        __syncthreads();
        s[threadIdx.x] += t;
        __syncthreads();
    }
    if (i < Nn) row_start[i] = pscan[blockIdx.x] + s[threadIdx.x] - v;
    if (blockIdx.x == 0 && threadIdx.x == 0) row_start[Nn] = E;
}

__global__ void k_scatter(const int* __restrict__ src, const int* __restrict__ dst,
                          const int* __restrict__ row_start, int* __restrict__ cursor,
                          int* __restrict__ csr, int E) {
    int i = blockIdx.x * blockDim.x + threadIdx.x;
    if (i < E) {
        int d = dst[i];
        int pos = row_start[d] + atomicAdd(&cursor[d], 1);
        csr[pos] = src[i];
    }
}

__global__ void k_cvt_feat(const float* __restrict__ f, float* __restrict__ out0,
                           unsigned int* __restrict__ hb, int total4) {
    int i = blockIdx.x * blockDim.x + threadIdx.x;
    if (i >= total4) return;
    float4 v = ((const float4*)f)[i];
    ((float4*)out0)[i] = v;
    unsigned int lo = (unsigned int)f2bf(v.x) | ((unsigned int)f2bf(v.y) << 16);
    unsigned int hi = (unsigned int)f2bf(v.z) | ((unsigned int)f2bf(v.w) << 16);
    ((uint2*)hb)[i] = make_uint2(lo, hi);
}

__global__ void k_cvtW(const float* __restrict__ W, unsigned short* __restrict__ Wt, int total) {
    int i = blockIdx.x * blockDim.x + threadIdx.x;
    if (i >= total) return;
    int l = i >> 14;
    int r = i & 16383;
    int k = r >> 7, n = r & 127;
    Wt[(l << 14) + n * 128 + k] = f2bf(W[i]);
}

__global__ void k_gather(const unsigned int* __restrict__ hb, const int* __restrict__ row_start,
                         const int* __restrict__ csr, const float* __restrict__ eps, int layer,
                         unsigned int* __restrict__ zb, int Nn) {
    int wv = threadIdx.x >> 6, lane = threadIdx.x & 63;
    int v = blockIdx.x * 4 + wv;
    if (v >= Nn) return;
    float e1 = 1.0f + eps[layer];
    unsigned int hs = hb[v * 64 + lane];
    float ax = e1 * bf16lo(hs);
    float ay = e1 * bf16hi(hs);
    int beg = row_start[v], end = row_start[v + 1];
    int e = beg;
    for (; e + 3 < end; e += 4) {
        int u0 = csr[e], u1 = csr[e + 1], u2 = csr[e + 2], u3 = csr[e + 3];
        unsigned int h0 = hb[u0 * 64 + lane];
        unsigned int h1 = hb[u1 * 64 + lane];
        unsigned int h2 = hb[u2 * 64 + lane];
        unsigned int h3 = hb[u3 * 64 + lane];
        ax += bf16lo(h0) + bf16lo(h1) + bf16lo(h2) + bf16lo(h3);
        ay += bf16hi(h0) + bf16hi(h1) + bf16hi(h2) + bf16hi(h3);
    }
    for (; e < end; e++) {
        unsigned int hu = hb[csr[e] * 64 + lane];
        ax += bf16lo(hu); ay += bf16hi(hu);
    }
    zb[v * 64 + lane] = (unsigned int)f2bf(ax) | ((unsigned int)f2bf(ay) << 16);
}

__launch_bounds__(256)
__global__ void k_gemm(const unsigned short* __restrict__ zb, const unsigned short* __restrict__ Wt,
                       const float* __restrict__ bias, int layer, float* __restrict__ y,
                       float* __restrict__ s1sum, float* __restrict__ s1sq, int Nn) {
    __shared__ unsigned short Al[64 * 136];
    __shared__ unsigned short Bl[128 * 136];
    int tid = threadIdx.x;
    int m0 = blockIdx.x * 64;
    const unsigned short* Wl = Wt + (layer << 14);
    #pragma unroll
    for (int p = 0; p < 8; p++) {
        int slot = p * 256 + tid;
        int n = slot >> 4, c = slot & 15;
        *(uint4*)&Bl[n * 136 + c * 8] = *(const uint4*)&Wl[n * 128 + c * 8];
    }
    #pragma unroll
    for (int p = 0; p < 4; p++) {
        int slot = p * 256 + tid;
        int r = slot >> 4, c = slot & 15;
        int grow = m0 + r;
        uint4 val = make_uint4(0, 0, 0, 0);
        if (grow < Nn) val = *(const uint4*)&zb[(size_t)grow * 128 + c * 8];
        *(uint4*)&Al[r * 136 + c * 8] = val;
    }
    __syncthreads();

    int lane = tid & 63, wv = tid >> 6;
    int tcol = lane & 15, quad = lane >> 4;
    f32x4 acc[4][2];
    #pragma unroll
    for (int a = 0; a < 4; a++)
        #pragma unroll
        for (int b2 = 0; b2 < 2; b2++) acc[a][b2] = (f32x4){0.f, 0.f, 0.f, 0.f};

    #pragma unroll
    for (int kk = 0; kk < 128; kk += 32) {
        int kb = kk + quad * 8;
        bfrag8 af[4], bf[2];
        #pragma unroll
        for (int mt = 0; mt < 4; mt++)
            af[mt] = *(const bfrag8*)&Al[(16 * mt + tcol) * 136 + kb];
        #pragma unroll
        for (int nt = 0; nt < 2; nt++)
            bf[nt] = *(const bfrag8*)&Bl[(32 * wv + 16 * nt + tcol) * 136 + kb];
        #pragma unroll
        for (int mt = 0; mt < 4; mt++)
            #pragma unroll
            for (int nt = 0; nt < 2; nt++)
                acc[mt][nt] = __builtin_amdgcn_mfma_f32_16x16x32_bf16(af[mt], bf[nt], acc[mt][nt], 0, 0, 0);
    }

    #pragma unroll
    for (int nt = 0; nt < 2; nt++) {
        int col = 32 * wv + 16 * nt + tcol;
        float bcol = bias[layer * 128 + col];
        float psum = 0.f, psq = 0.f;
        #pragma unroll
        for (int mt = 0; mt < 4; mt++) {
            #pragma unroll
            for (int r = 0; r < 4; r++) {
                int row = m0 + 16 * mt + quad * 4 + r;
                float val = acc[mt][nt][r] + bcol;
                if (row < Nn) {
                    y[(size_t)row * 128 + col] = val;
                    psum += val;
                    psq += val * val;
                }
            }
        }
        psum += __shfl_xor(psum, 16); psq += __shfl_xor(psq, 16);
        psum += __shfl_xor(psum, 32); psq += __shfl_xor(psq, 32);
        if (lane < 16) {
            atomicAdd(&s1sum[col], psum);
            atomicAdd(&s1sq[col], psq);
        }
    }
}

__global__ void k_fin(float* __restrict__ sum, float* __restrict__ sq,
                      const float* __restrict__ gamma, const float* __restrict__ beta, int layer,
                      float* __restrict__ sc, float* __restrict__ sh, float invN) {
    int c = threadIdx.x;
    float m = sum[c] * invN;
    float var = sq[c] * invN - m * m;
    float rstd = rsqrtf(var + 1e-5f);
    float s = gamma[layer * 128 + c] * rstd;
    sc[c] = s;
    sh[c] = beta[layer * 128 + c] - m * s;
    sum[c] = 0.f;
    sq[c] = 0.f;
}

__global__ void k_stats2(const float* __restrict__ y, const float* __restrict__ s1,
                         const float* __restrict__ sh1, float* __restrict__ s2sum,
                         float* __restrict__ s2sq, int Nn) {
    int c = threadIdx.x & 127;
    int r0 = blockIdx.x * 2 + (threadIdx.x >> 7);
    float sc = s1[c], sh = sh1[c];
    float sum = 0.f, sq = 0.f;
    int stride = gridDim.x * 2;
    for (int r = r0; r < Nn; r += stride) {
        float t = fmaxf(y[(size_t)r * 128 + c] * sc + sh, 0.f);
        sum += t;
        sq += t * t;
    }
    atomicAdd(&s2sum[c], sum);
    atomicAdd(&s2sq[c], sq);
}

__global__ void k_apply(float* __restrict__ y, const float* __restrict__ s1,
                        const float* __restrict__ sh1, const float* __restrict__ s2,
                        const float* __restrict__ sh2, unsigned int* __restrict__ hb, int total4) {
    int i = blockIdx.x * blockDim.x + threadIdx.x;
    if (i >= total4) return;
    int c = (i * 4) & 127;
    float4 v = ((float4*)y)[i];
    float t0 = fmaxf(v.x * s1[c] + sh1[c], 0.f);
    float t1 = fmaxf(v.y * s1[c + 1] + sh1[c + 1], 0.f);
    float t2 = fmaxf(v.z * s1[c + 2] + sh1[c + 2], 0.f);
    float t3 = fmaxf(v.w * s1[c + 3] + sh1[c + 3], 0.f);
    float o0 = fmaxf(t0 * s2[c] + sh2[c], 0.f);
    float o1 = fmaxf(t1 * s2[c + 1] + sh2[c + 1], 0.f);
    float o2 = fmaxf(t2 * s2[c + 2] + sh2[c + 2], 0.f);
    float o3 = fmaxf(t3 * s2[c + 3] + sh2[c + 3], 0.f);
    ((float4*)y)[i] = make_float4(o0, o1, o2, o3);
    unsigned int lo = (unsigned int)f2bf(o0) | ((unsigned int)f2bf(o1) << 16);
    unsigned int hi = (unsigned int)f2bf(o2) | ((unsigned int)f2bf(o3) << 16);
    ((uint2*)hb)[i] = make_uint2(lo, hi);
}

extern "C" void kernel_launch(void* const* d_in, const int* in_sizes, int n_in,
                              void* d_out, int out_size, void* d_ws, size_t ws_size,
                              hipStream_t stream) {
    const float* features = (const float*)d_in[0];
    const float* W        = (const float*)d_in[1];
    const float* bias     = (const float*)d_in[2];
    const float* eps      = (const float*)d_in[3];
    const float* g1       = (const float*)d_in[4];
    const float* b1       = (const float*)d_in[5];
    const float* g2       = (const float*)d_in[6];
    const float* b2       = (const float*)d_in[7];
    const int*   src      = (const int*)d_in[8];
    const int*   dst      = (const int*)d_in[9];

    const int Nn = in_sizes[0] / DD;   // 100000
    const int E  = in_sizes[8];        // 1600000
    float* out = (float*)d_out;

    // workspace carve-up (shared by both paths)
    char* w = (char*)d_ws;
    auto alloc = [&](size_t bytes) -> char* {
        char* p = w;
        w += (bytes + 255) & ~(size_t)255;
        return p;
    };
    int* deg       = (int*)alloc((size_t)Nn * 4);
    int* cursor    = (int*)alloc((size_t)Nn * 4);
    int* row_start = (int*)alloc((size_t)(Nn + 1) * 4);
    int* partials  = (int*)alloc(1024);
    int* pscan     = (int*)alloc(1024);
    int* csr       = (int*)alloc((size_t)E * 4);
    unsigned int* hb = (unsigned int*)alloc((size_t)Nn * 64 * 4);
    unsigned int* zb = (unsigned int*)alloc((size_t)Nn * 64 * 4);
    unsigned short* Wt = (unsigned short*)alloc((size_t)3 * 128 * 128 * 2);
    float* yb   = (float*)alloc((size_t)Nn * 128 * 4);
    float* stats = (float*)alloc(3 * 512 * 4);   // mega: [3][4][128]
    float* s1    = (float*)alloc(512);
    float* sh1   = (float*)alloc(512);
    float* s2    = (float*)alloc(512);
    float* sh2   = (float*)alloc(512);

    const int total4 = Nn * DD / 4;
    const float invN = 1.0f / (float)Nn;

    MegaArgs ma;
    ma.features = features; ma.W = W; ma.bias = bias; ma.eps = eps;
    ma.g1 = g1; ma.b1 = b1; ma.g2 = g2; ma.b2 = b2;
    ma.src = src; ma.dst = dst; ma.out = out;
    ma.Nn = Nn; ma.E = E;
    ma.ntiles = (Nn + 63) / 64;
    ma.nchunk = (Nn + 511) / 512;
    ma.total4 = total4;
    ma.invN = invN;
    ma.deg = deg; ma.cursor = cursor; ma.row_local = row_start;
    ma.partials = partials; ma.pscan = pscan; ma.csr = csr;
    ma.hb = hb; ma.Wt = Wt; ma.y = yb; ma.stats = stats;

    int occ = 0;
    hipError_t oe = hipOccupancyMaxActiveBlocksPerMultiprocessor(&occ, (const void*)k_mega, 256, 0);
    int bpc = (oe == hipSuccess && occ > 0) ? occ : 2;
    if (bpc > 3) bpc = 3;
    int grid = 256 * bpc;   // 256 CUs on MI355X

    void* kargs[] = { &ma };
    hipError_t err = hipLaunchCooperativeKernel((void*)k_mega, dim3(grid), dim3(256),
                                                kargs, 0, stream);
    if (err == hipSuccess) return;

    // ---------------- fallback: round-1 known-good path ----------------
    hipMemsetAsync(deg, 0, (size_t)Nn * 4, stream);
    hipMemsetAsync(cursor, 0, (size_t)Nn * 4, stream);
    hipMemsetAsync(stats, 0, 3 * 512 * 4, stream);

    const int nb = (Nn + 1023) / 1024;
    float* s1sum = stats;        // reuse first 4*128 of stats as the 4 accumulators
    float* s1sq  = stats + 128;
    float* s2sum = stats + 256;
    float* s2sq  = stats + 384;

    k_hist<<<(E + 255) / 256, 256, 0, stream>>>(dst, deg, E);
    k_scan1<<<nb, 1024, 0, stream>>>(deg, partials, Nn);
    k_scan2<<<1, 64, 0, stream>>>(partials, pscan, nb);
    k_scan3<<<nb, 1024, 0, stream>>>(deg, pscan, row_start, Nn, E);
    k_scatter<<<(E + 255) / 256, 256, 0, stream>>>(src, dst, row_start, cursor, csr, E);
    k_cvt_feat<<<(total4 + 255) / 256, 256, 0, stream>>>(features, out, hb, total4);
    k_cvtW<<<(3 * 128 * 128 + 255) / 256, 256, 0, stream>>>(W, Wt, 3 * 128 * 128);

    for (int l = 0; l < 3; l++) {
        float* y = out + (size_t)(l + 1) * Nn * DD;
        k_gather<<<(Nn + 3) / 4, 256, 0, stream>>>(hb, row_start, csr, eps, l, zb, Nn);
        k_gemm<<<(Nn + 63) / 64, 256, 0, stream>>>((const unsigned short*)zb, Wt, bias, l, y,
                                                   s1sum, s1sq, Nn);
        k_fin<<<1, 128, 0, stream>>>(s1sum, s1sq, g1, b1, l, s1, sh1, invN);
        k_stats2<<<512, 256, 0, stream>>>(y, s1, sh1, s2sum, s2sq, Nn);
        k_fin<<<1, 128, 0, stream>>>(s2sum, s2sq, g2, b2, l, s2, sh2, invN);
        k_apply<<<(total4 + 255) / 256, 256, 0, stream>>>(y, s1, sh1, s2, sh2, hb, total4);
    }
}

// Round 3
// 865.475 us; speedup vs baseline: 2.3450x; 2.3450x over previous
//
#include <hip/hip_runtime.h>
#include <hip/hip_bf16.h>

#define DD 128

typedef __attribute__((ext_vector_type(8))) short bfrag8;
typedef __attribute__((ext_vector_type(4))) float f32x4;

__device__ __forceinline__ float bf16lo(unsigned int u) {
    union { unsigned int i; float f; } c; c.i = u << 16; return c.f;
}
__device__ __forceinline__ float bf16hi(unsigned int u) {
    union { unsigned int i; float f; } c; c.i = u & 0xffff0000u; return c.f;
}
__device__ __forceinline__ unsigned short f2bf(float f) {
    union { float f; unsigned int i; } c; c.f = f;
    unsigned int x = c.i;
    unsigned int r = (x + 0x7fffu + ((x >> 16) & 1u)) >> 16;  // RNE
    return (unsigned short)r;
}

// ---------------- setup: degree histogram + feature convert + W convert ----------------
__global__ void k_setup(const int* __restrict__ dst, int* __restrict__ deg, int E,
                        const float* __restrict__ features, float* __restrict__ out0,
                        unsigned int* __restrict__ hb, int total4,
                        const float* __restrict__ W, unsigned short* __restrict__ Wt) {
    int gtid = blockIdx.x * blockDim.x + threadIdx.x;
    int gsz = gridDim.x * blockDim.x;
    for (int i = gtid; i < E; i += gsz) atomicAdd(&deg[dst[i]], 1);
    for (int i = gtid; i < total4; i += gsz) {
        float4 v = ((const float4*)features)[i];
        ((float4*)out0)[i] = v;
        unsigned int lo = (unsigned int)f2bf(v.x) | ((unsigned int)f2bf(v.y) << 16);
        unsigned int hi = (unsigned int)f2bf(v.z) | ((unsigned int)f2bf(v.w) << 16);
        ((uint2*)hb)[i] = make_uint2(lo, hi);
    }
    for (int i = gtid; i < 3 * 128 * 128; i += gsz) {
        int l = i >> 14, r = i & 16383, k = r >> 7, n = r & 127;
        Wt[(l << 14) + n * 128 + k] = f2bf(W[i]);
    }
}

// ---------------- scan stage 1: per-1024-chunk degree sums ----------------
__global__ void k_scan1(const int* __restrict__ deg, int* __restrict__ partials, int Nn) {
    __shared__ int sm[256];
    int tid = threadIdx.x;
    int base = (blockIdx.x << 10) + 4 * tid;
    int s = 0;
    if (base + 3 < Nn) {
        int4 v = *(const int4*)&deg[base];
        s = v.x + v.y + v.z + v.w;
    } else {
        for (int j = 0; j < 4; j++) if (base + j < Nn) s += deg[base + j];
    }
    sm[tid] = s;
    __syncthreads();
    for (int off = 128; off > 0; off >>= 1) {
        if (tid < off) sm[tid] += sm[tid + off];
        __syncthreads();
    }
    if (tid == 0) partials[blockIdx.x] = sm[0];
}

// ---------------- scan stage 2: final row_start (each block redoes the 98-entry top scan) ----------------
__global__ void k_scan3(const int* __restrict__ deg, const int* __restrict__ partials,
                        int* __restrict__ row_start, int Nn, int E, int nchunk) {
    __shared__ int sp[256];
    __shared__ int sm[256];
    int tid = threadIdx.x, c = blockIdx.x;
    int p = (tid < nchunk) ? partials[tid] : 0;
    sp[tid] = p;
    __syncthreads();
    for (int off = 1; off < 256; off <<= 1) {
        int t = (tid >= off) ? sp[tid - off] : 0;
        __syncthreads();
        sp[tid] += t;
        __syncthreads();
    }
    int chunkpref = (c == 0) ? 0 : sp[c - 1];

    int base = (c << 10) + 4 * tid;
    int d0 = 0, d1 = 0, d2 = 0, d3 = 0;
    if (base + 3 < Nn) {
        int4 v = *(const int4*)&deg[base];
        d0 = v.x; d1 = v.y; d2 = v.z; d3 = v.w;
    } else {
        if (base + 0 < Nn) d0 = deg[base + 0];
        if (base + 1 < Nn) d1 = deg[base + 1];
        if (base + 2 < Nn) d2 = deg[base + 2];
        if (base + 3 < Nn) d3 = deg[base + 3];
    }
    int ts = d0 + d1 + d2 + d3;
    sm[tid] = ts;
    __syncthreads();
    for (int off = 1; off < 256; off <<= 1) {
        int t = (tid >= off) ? sm[tid - off] : 0;
        __syncthreads();
        sm[tid] += t;
        __syncthreads();
    }
    int run = chunkpref + sm[tid] - ts;
    if (base + 0 < Nn) row_start[base + 0] = run; run += d0;
    if (base + 1 < Nn) row_start[base + 1] = run; run += d1;
    if (base + 2 < Nn) row_start[base + 2] = run; run += d2;
    if (base + 3 < Nn) row_start[base + 3] = run;
    if (c == 0 && tid == 0) row_start[Nn] = E;
}

// ---------------- scatter edges into CSR ----------------
__global__ void k_scatter(const int* __restrict__ src, const int* __restrict__ dst,
                          const int* __restrict__ row_start, int* __restrict__ cursor,
                          int* __restrict__ csr, int E) {
    int i = blockIdx.x * blockDim.x + threadIdx.x;
    if (i < E) {
        int d = dst[i];
        int pos = row_start[d] + atomicAdd(&cursor[d], 1);
        csr[pos] = src[i];
    }
}

// ---------------- gather: z = (1+eps)*h + sum_{u in N(v)} h_u ----------------
__global__ void k_gather(const unsigned int* __restrict__ hb, const int* __restrict__ row_start,
                         const int* __restrict__ csr, const float* __restrict__ eps, int layer,
                         unsigned int* __restrict__ zb, int Nn) {
    int wv = threadIdx.x >> 6, lane = threadIdx.x & 63;
    int v = blockIdx.x * 4 + wv;
    if (v >= Nn) return;
    float e1 = 1.0f + eps[layer];
    unsigned int hs = hb[(size_t)v * 64 + lane];
    float ax = e1 * bf16lo(hs);
    float ay = e1 * bf16hi(hs);
    int beg = row_start[v], end = row_start[v + 1];
    int e = beg;
    for (; e + 7 < end; e += 8) {
        int u0 = csr[e], u1 = csr[e + 1], u2 = csr[e + 2], u3 = csr[e + 3];
        int u4 = csr[e + 4], u5 = csr[e + 5], u6 = csr[e + 6], u7 = csr[e + 7];
        unsigned int h0 = hb[(size_t)u0 * 64 + lane];
        unsigned int h1 = hb[(size_t)u1 * 64 + lane];
        unsigned int h2 = hb[(size_t)u2 * 64 + lane];
        unsigned int h3 = hb[(size_t)u3 * 64 + lane];
        unsigned int h4 = hb[(size_t)u4 * 64 + lane];
        unsigned int h5 = hb[(size_t)u5 * 64 + lane];
        unsigned int h6 = hb[(size_t)u6 * 64 + lane];
        unsigned int h7 = hb[(size_t)u7 * 64 + lane];
        ax += bf16lo(h0) + bf16lo(h1) + bf16lo(h2) + bf16lo(h3)
            + bf16lo(h4) + bf16lo(h5) + bf16lo(h6) + bf16lo(h7);
        ay += bf16hi(h0) + bf16hi(h1) + bf16hi(h2) + bf16hi(h3)
            + bf16hi(h4) + bf16hi(h5) + bf16hi(h6) + bf16hi(h7);
    }
    for (; e < end; e++) {
        unsigned int hu = hb[(size_t)csr[e] * 64 + lane];
        ax += bf16lo(hu); ay += bf16hi(hu);
    }
    zb[(size_t)v * 64 + lane] = (unsigned int)f2bf(ax) | ((unsigned int)f2bf(ay) << 16);
}

// ---------------- GEMM: y = z @ W + b, fused BN1 column stats (atomics into stl) ----------------
__launch_bounds__(256)
__global__ void k_gemm(const unsigned short* __restrict__ zb, const unsigned short* __restrict__ Wt,
                       const float* __restrict__ bias, int layer, float* __restrict__ y,
                       float* __restrict__ stl, int Nn) {
    __shared__ unsigned short Al[64 * 136];
    __shared__ unsigned short Bl[128 * 136];
    int tid = threadIdx.x;
    int m0 = blockIdx.x * 64;
    const unsigned short* Wl = Wt + (layer << 14);
    #pragma unroll
    for (int p = 0; p < 8; p++) {
        int slot = p * 256 + tid;
        int n = slot >> 4, c = slot & 15;
        *(uint4*)&Bl[n * 136 + c * 8] = *(const uint4*)&Wl[n * 128 + c * 8];
    }
    #pragma unroll
    for (int p = 0; p < 4; p++) {
        int slot = p * 256 + tid;
        int r = slot >> 4, c = slot & 15;
        int grow = m0 + r;
        uint4 val = make_uint4(0, 0, 0, 0);
        if (grow < Nn) val = *(const uint4*)&zb[(size_t)grow * 128 + c * 8];
        *(uint4*)&Al[r * 136 + c * 8] = val;
    }
    __syncthreads();

    int lane = tid & 63, wv = tid >> 6;
    int tcol = lane & 15, quad = lane >> 4;
    f32x4 acc[4][2];
    #pragma unroll
    for (int a = 0; a < 4; a++)
        #pragma unroll
        for (int b2 = 0; b2 < 2; b2++) acc[a][b2] = (f32x4){0.f, 0.f, 0.f, 0.f};

    #pragma unroll
    for (int kk = 0; kk < 128; kk += 32) {
        int kb = kk + quad * 8;
        bfrag8 af[4], bf[2];
        #pragma unroll
        for (int mt = 0; mt < 4; mt++)
            af[mt] = *(const bfrag8*)&Al[(16 * mt + tcol) * 136 + kb];
        #pragma unroll
        for (int nt = 0; nt < 2; nt++)
            bf[nt] = *(const bfrag8*)&Bl[(32 * wv + 16 * nt + tcol) * 136 + kb];
        #pragma unroll
        for (int mt = 0; mt < 4; mt++)
            #pragma unroll
            for (int nt = 0; nt < 2; nt++)
                acc[mt][nt] = __builtin_amdgcn_mfma_f32_16x16x32_bf16(af[mt], bf[nt], acc[mt][nt], 0, 0, 0);
    }

    #pragma unroll
    for (int nt = 0; nt < 2; nt++) {
        int col = 32 * wv + 16 * nt + tcol;
        float bcol = bias[layer * 128 + col];
        float psum = 0.f, psq = 0.f;
        #pragma unroll
        for (int mt = 0; mt < 4; mt++) {
            #pragma unroll
            for (int r = 0; r < 4; r++) {
                int row = m0 + 16 * mt + quad * 4 + r;
                float val = acc[mt][nt][r] + bcol;
                if (row < Nn) {
                    y[(size_t)row * 128 + col] = val;
                    psum += val;
                    psq += val * val;
                }
            }
        }
        psum += __shfl_xor(psum, 16); psq += __shfl_xor(psq, 16);
        psum += __shfl_xor(psum, 32); psq += __shfl_xor(psq, 32);
        if (lane < 16) {
            atomicAdd(&stl[col], psum);
            atomicAdd(&stl[128 + col], psq);
        }
    }
}

// ---------------- BN2 stats over relu(aff1(y)); BN1 scale/shift derived in-block ----------------
__launch_bounds__(256)
__global__ void k_stats2(const float* __restrict__ y, float* __restrict__ stl,
                         const float* __restrict__ g1, const float* __restrict__ b1,
                         int layer, int total4, float invN) {
    __shared__ float red[512];
    int tid = threadIdx.x;
    if (tid < 128) {
        float m = stl[tid] * invN;
        float var = stl[128 + tid] * invN - m * m;
        float rstd = rsqrtf(var + 1e-5f);
        float s = g1[layer * 128 + tid] * rstd;
        red[tid] = s;
        red[128 + tid] = b1[layer * 128 + tid] - m * s;
        red[256 + tid] = 0.f;
        red[384 + tid] = 0.f;
    }
    __syncthreads();
    int lane = tid & 63;
    int cbase = (4 * tid) & 127;
    float s1r[4], sh1r[4];
    #pragma unroll
    for (int j = 0; j < 4; j++) { s1r[j] = red[cbase + j]; sh1r[j] = red[128 + cbase + j]; }
    float ps[4] = {0.f, 0.f, 0.f, 0.f}, pq[4] = {0.f, 0.f, 0.f, 0.f};
    int gtid = blockIdx.x * 256 + tid;
    int gsz = gridDim.x * 256;
    for (int i = gtid; i < total4; i += gsz) {
        float4 v = ((const float4*)y)[i];
        float t0 = fmaxf(v.x * s1r[0] + sh1r[0], 0.f);
        float t1 = fmaxf(v.y * s1r[1] + sh1r[1], 0.f);
        float t2 = fmaxf(v.z * s1r[2] + sh1r[2], 0.f);
        float t3 = fmaxf(v.w * s1r[3] + sh1r[3], 0.f);
        ps[0] += t0; pq[0] += t0 * t0;
        ps[1] += t1; pq[1] += t1 * t1;
        ps[2] += t2; pq[2] += t2 * t2;
        ps[3] += t3; pq[3] += t3 * t3;
    }
    #pragma unroll
    for (int j = 0; j < 4; j++) {
        ps[j] += __shfl_xor(ps[j], 32);
        pq[j] += __shfl_xor(pq[j], 32);
    }
    if (lane < 32) {
        #pragma unroll
        for (int j = 0; j < 4; j++) {
            atomicAdd(&red[256 + cbase + j], ps[j]);
            atomicAdd(&red[384 + cbase + j], pq[j]);
        }
    }
    __syncthreads();
    if (tid < 128) {
        atomicAdd(&stl[256 + tid], red[256 + tid]);
        atomicAdd(&stl[384 + tid], red[384 + tid]);
    }
}

// ---------------- apply both BNs (scale/shift derived in-block), write out slab + bf16 h ----------------
__launch_bounds__(256)
__global__ void k_apply(const float* __restrict__ y, const float* __restrict__ stl,
                        const float* __restrict__ g1, const float* __restrict__ b1,
                        const float* __restrict__ g2, const float* __restrict__ b2,
                        int layer, float* __restrict__ outl, unsigned int* __restrict__ hb,
                        int total4, float invN) {
    __shared__ float red[512];
    int tid = threadIdx.x;
    if (tid < 128) {
        float m1 = stl[tid] * invN;
        float v1 = stl[128 + tid] * invN - m1 * m1;
        float r1 = rsqrtf(v1 + 1e-5f);
        float s1 = g1[layer * 128 + tid] * r1;
        red[tid] = s1;
        red[128 + tid] = b1[layer * 128 + tid] - m1 * s1;
        float m2 = stl[256 + tid] * invN;
        float v2 = stl[384 + tid] * invN - m2 * m2;
        float r2 = rsqrtf(v2 + 1e-5f);
        float s2 = g2[layer * 128 + tid] * r2;
        red[256 + tid] = s2;
        red[384 + tid] = b2[layer * 128 + tid] - m2 * s2;
    }
    __syncthreads();
    int cbase = (4 * tid) & 127;
    float s1a[4], sh1a[4], s2a[4], sh2a[4];
    #pragma unroll
    for (int j = 0; j < 4; j++) {
        s1a[j]  = red[cbase + j];       sh1a[j] = red[128 + cbase + j];
        s2a[j]  = red[256 + cbase + j]; sh2a[j] = red[384 + cbase + j];
    }
    int gtid = blockIdx.x * 256 + tid;
    int gsz = gridDim.x * 256;
    for (int i = gtid; i < total4; i += gsz) {
        float4 v = ((const float4*)y)[i];
        float t0 = fmaxf(v.x * s1a[0] + sh1a[0], 0.f);
        float t1 = fmaxf(v.y * s1a[1] + sh1a[1], 0.f);
        float t2 = fmaxf(v.z * s1a[2] + sh1a[2], 0.f);
        float t3 = fmaxf(v.w * s1a[3] + sh1a[3], 0.f);
        float o0 = fmaxf(t0 * s2a[0] + sh2a[0], 0.f);
        float o1 = fmaxf(t1 * s2a[1] + sh2a[1], 0.f);
        float o2 = fmaxf(t2 * s2a[2] + sh2a[2], 0.f);
        float o3 = fmaxf(t3 * s2a[3] + sh2a[3], 0.f);
        ((float4*)outl)[i] = make_float4(o0, o1, o2, o3);
        unsigned int lo = (unsigned int)f2bf(o0) | ((unsigned int)f2bf(o1) << 16);
        unsigned int hi = (unsigned int)f2bf(o2) | ((unsigned int)f2bf(o3) << 16);
        ((uint2*)hb)[i] = make_uint2(lo, hi);
    }
}

extern "C" void kernel_launch(void* const* d_in, const int* in_sizes, int n_in,
                              void* d_out, int out_size, void* d_ws, size_t ws_size,
                              hipStream_t stream) {
    const float* features = (const float*)d_in[0];
    const float* W        = (const float*)d_in[1];
    const float* bias     = (const float*)d_in[2];
    const float* eps      = (const float*)d_in[3];
    const float* g1       = (const float*)d_in[4];
    const float* b1       = (const float*)d_in[5];
    const float* g2       = (const float*)d_in[6];
    const float* b2       = (const float*)d_in[7];
    const int*   src      = (const int*)d_in[8];
    const int*   dst      = (const int*)d_in[9];

    const int Nn = in_sizes[0] / DD;   // 100000
    const int E  = in_sizes[8];        // 1600000
    float* out = (float*)d_out;

    char* w = (char*)d_ws;
    auto alloc = [&](size_t bytes) -> char* {
        char* p = w;
        w += (bytes + 255) & ~(size_t)255;
        return p;
    };
    // zero-span group (contiguous): deg, cursor, stats
    int*   deg    = (int*)alloc((size_t)Nn * 4);
    int*   cursor = (int*)alloc((size_t)Nn * 4);
    float* stats  = (float*)alloc(3 * 512 * 4);   // [3][4][128]
    char*  zero_end = w;
    int* row_start = (int*)alloc((size_t)(Nn + 1) * 4);
    int* partials  = (int*)alloc(1024);
    int* csr       = (int*)alloc((size_t)E * 4);
    unsigned int* hb = (unsigned int*)alloc((size_t)Nn * 64 * 4);
    unsigned int* zb = (unsigned int*)alloc((size_t)Nn * 64 * 4);
    unsigned short* Wt = (unsigned short*)alloc((size_t)3 * 128 * 128 * 2);
    float* yb = (float*)alloc((size_t)Nn * 128 * 4);

    const int total4 = Nn * DD / 4;
    const float invN = 1.0f / (float)Nn;
    const int nchunk = (Nn + 1023) / 1024;   // 98

    hipMemsetAsync(deg, 0, (size_t)(zero_end - (char*)deg), stream);

    k_setup<<<(E + 255) / 256, 256, 0, stream>>>(dst, deg, E, features, out, hb, total4, W, Wt);
    k_scan1<<<nchunk, 256, 0, stream>>>(deg, partials, Nn);
    k_scan3<<<nchunk, 256, 0, stream>>>(deg, partials, row_start, Nn, E, nchunk);
    k_scatter<<<(E + 255) / 256, 256, 0, stream>>>(src, dst, row_start, cursor, csr, E);

    for (int l = 0; l < 3; l++) {
        float* stl = stats + l * 512;
        float* outl = out + (size_t)(l + 1) * Nn * DD;
        k_gather<<<(Nn + 3) / 4, 256, 0, stream>>>(hb, row_start, csr, eps, l, zb, Nn);
        k_gemm<<<(Nn + 63) / 64, 256, 0, stream>>>((const unsigned short*)zb, Wt, bias, l, yb,
                                                   stl, Nn);
        k_stats2<<<512, 256, 0, stream>>>(yb, stl, g1, b1, l, total4, invN);
        k_apply<<<1024, 256, 0, stream>>>(yb, stl, g1, b1, g2, b2, l, outl, hb, total4, invN);
    }
}